// Round 1
// baseline (440.909 us; speedup 1.0000x reference)
//
#include <hip/hip_runtime.h>

#define DEVI __device__ __forceinline__

typedef __attribute__((ext_vector_type(8))) short short8;
typedef __attribute__((ext_vector_type(4))) float f32x4;

struct alignas(8) us4 { unsigned short a, b, c, d; };

DEVI unsigned short f2bf(float f) {
    unsigned int u = __float_as_uint(f);
    u += 0x7fffU + ((u >> 16) & 1U);   // round-to-nearest-even
    return (unsigned short)(u >> 16);
}

DEVI f32x4 mfma16(short8 a, short8 b, f32x4 c) {
    return __builtin_amdgcn_mfma_f32_16x16x32_bf16(a, b, c, 0, 0, 0);
}

// ---------------------------------------------------------------------------
// Weight transpose + bf16 convert: wT[n][k] = (bf16) w[k][n], 512x512, z = 0..5
// ---------------------------------------------------------------------------
__global__ __launch_bounds__(256) void trans_kernel(
    const float* w0, const float* w1, const float* w2, const float* w3,
    const float* w4, const float* w5, short* wT)
{
    const float* srcs[6] = {w0, w1, w2, w3, w4, w5};
    const float* src = srcs[blockIdx.z];
    short* dst = wT + (size_t)blockIdx.z * 512 * 512;
    int k0 = blockIdx.x * 64, n0 = blockIdx.y * 64;
    __shared__ float tile[64][65];
    int t = threadIdx.x;
    int r = t >> 2, c0 = (t & 3) * 16;
#pragma unroll
    for (int ii = 0; ii < 4; ++ii) {
        float4 v = *(const float4*)(src + (size_t)(k0 + r) * 512 + n0 + c0 + ii * 4);
        tile[r][c0 + ii * 4 + 0] = v.x;
        tile[r][c0 + ii * 4 + 1] = v.y;
        tile[r][c0 + ii * 4 + 2] = v.z;
        tile[r][c0 + ii * 4 + 3] = v.w;
    }
    __syncthreads();
#pragma unroll
    for (int ii = 0; ii < 4; ++ii) {
        us4 o;
        o.a = f2bf(tile[c0 + ii * 4 + 0][r]);
        o.b = f2bf(tile[c0 + ii * 4 + 1][r]);
        o.c = f2bf(tile[c0 + ii * 4 + 2][r]);
        o.d = f2bf(tile[c0 + ii * 4 + 3][r]);
        *(us4*)(dst + (size_t)(n0 + r) * 512 + k0 + c0 + ii * 4) = o;
    }
}

// ---------------------------------------------------------------------------
// Input projections: z=0: QK=x@w_qk (natural [bh][i][d])
//                    z=1: CQK=ctx@w_cqk (natural)
//                    z=2: VT=x@w_v (transposed [bh][d][i])
//                    z=3: CVT=ctx@w_cv (transposed)
// ---------------------------------------------------------------------------
__global__ __launch_bounds__(256) void proj_kernel(
    const float* __restrict__ x, const float* __restrict__ ctx,
    const short* __restrict__ wT,
    short* __restrict__ QK, short* __restrict__ CQK,
    short* __restrict__ VT, short* __restrict__ CVT)
{
    int p = blockIdx.z;
    const float* src = (p == 0 || p == 2) ? x : ctx;
    const short* w = wT + (size_t)p * 512 * 512;
    int wid = threadIdx.x >> 6, lane = threadIdx.x & 63, il = lane & 15, q = lane >> 4;
    int mb = blockIdx.x * 64 + wid * 16;
    int nb = blockIdx.y * 64;
    const float* arow = src + (size_t)(mb + il) * 512 + q * 8;
    f32x4 acc[4] = {};
    for (int kk = 0; kk < 16; ++kk) {
        float4 fa = *(const float4*)(arow + kk * 32);
        float4 fb = *(const float4*)(arow + kk * 32 + 4);
        short8 a;
        a[0] = (short)f2bf(fa.x); a[1] = (short)f2bf(fa.y);
        a[2] = (short)f2bf(fa.z); a[3] = (short)f2bf(fa.w);
        a[4] = (short)f2bf(fb.x); a[5] = (short)f2bf(fb.y);
        a[6] = (short)f2bf(fb.z); a[7] = (short)f2bf(fb.w);
#pragma unroll
        for (int nj = 0; nj < 4; ++nj) {
            short8 b = *(const short8*)(w + (size_t)(nb + nj * 16 + il) * 512 + kk * 32 + q * 8);
            acc[nj] = mfma16(a, b, acc[nj]);
        }
    }
    if (p < 2) {
        short* dst = (p == 0) ? QK : CQK;
#pragma unroll
        for (int nj = 0; nj < 4; ++nj) {
            int c = nb + nj * 16 + il;
            int h = c >> 6, d = c & 63;
#pragma unroll
            for (int r = 0; r < 4; ++r) {
                int m = mb + q * 4 + r;
                int b_ = m >> 11, i = m & 2047;
                dst[(((size_t)b_ * 8 + h) * 2048 + i) * 64 + d] = (short)f2bf(acc[nj][r]);
            }
        }
    } else {
        short* dst = (p == 2) ? VT : CVT;
#pragma unroll
        for (int nj = 0; nj < 4; ++nj) {
            int c = nb + nj * 16 + il;
            int h = c >> 6, d = c & 63;
            int m0 = mb + q * 4;
            int b_ = m0 >> 11, i0 = m0 & 2047;
            us4 o;
            o.a = f2bf(acc[nj][0]); o.b = f2bf(acc[nj][1]);
            o.c = f2bf(acc[nj][2]); o.d = f2bf(acc[nj][3]);
            *(us4*)(dst + (((size_t)b_ * 8 + h) * 64 + d) * 2048 + i0) = o;
        }
    }
}

// ---------------------------------------------------------------------------
// Fused attention pass (used twice, operands swapped for the column softmax):
//   Om[b][row][h*64+d] = ( sum_t exp2(C*(A[row]·B[t])) * W[d][t] ) / sum_t exp2(...)
// A-rows held in regs; sim via MFMA; P tile round-trips per-wave LDS; PV via MFMA.
// ---------------------------------------------------------------------------
__global__ __launch_bounds__(256) void attn_kernel(
    const short* __restrict__ Arows, const short* __restrict__ Bcols,
    const short* __restrict__ WT, short* __restrict__ Om)
{
    __shared__ __align__(16) short p_lds[2][4][16][72];
    int bh = blockIdx.x, ib = blockIdx.y;
    int b_ = bh >> 3, h = bh & 7;
    int w = threadIdx.x >> 6, lane = threadIdx.x & 63, il = lane & 15, q = lane >> 4;
    const short* Ab = Arows + (size_t)bh * 2048 * 64;
    const short* Bb = Bcols + (size_t)bh * 2048 * 64;
    const short* Wb = WT + (size_t)bh * 64 * 2048;
    int i_row = ib * 64 + w * 16 + il;
    short8 aq0 = *(const short8*)(Ab + (size_t)i_row * 64 + q * 8);
    short8 aq1 = *(const short8*)(Ab + (size_t)i_row * 64 + 32 + q * 8);
    f32x4 acc[4] = {};
    float s_part[4] = {0.f, 0.f, 0.f, 0.f};
    const float C = 0.18033688011112042f;  // log2(e) / 8  (folds SCALE into exp2)
    for (int jt = 0; jt < 32; ++jt) {
        int j0 = jt * 64;
        int pb = jt & 1;
        f32x4 sim[4];
#pragma unroll
        for (int nj = 0; nj < 4; ++nj) {
            const short* bp = Bb + (size_t)(j0 + nj * 16 + il) * 64 + q * 8;
            short8 b0 = *(const short8*)(bp);
            short8 b1 = *(const short8*)(bp + 32);
            f32x4 z = {};
            z = mfma16(aq0, b0, z);
            sim[nj] = mfma16(aq1, b1, z);
        }
#pragma unroll
        for (int nj = 0; nj < 4; ++nj) {
#pragma unroll
            for (int r = 0; r < 4; ++r) {
                float pv = __builtin_amdgcn_exp2f(sim[nj][r] * C);
                s_part[r] += pv;
                p_lds[pb][w][q * 4 + r][nj * 16 + il] = (short)f2bf(pv);
            }
        }
        short8 pa0 = *(const short8*)(&p_lds[pb][w][il][q * 8]);
        short8 pa1 = *(const short8*)(&p_lds[pb][w][il][32 + q * 8]);
#pragma unroll
        for (int nd = 0; nd < 4; ++nd) {
            const short* vp = Wb + (size_t)(nd * 16 + il) * 2048 + j0 + q * 8;
            short8 v0 = *(const short8*)(vp);
            short8 v1 = *(const short8*)(vp + 32);
            acc[nd] = mfma16(pa0, v0, acc[nd]);
            acc[nd] = mfma16(pa1, v1, acc[nd]);
        }
    }
#pragma unroll
    for (int r = 0; r < 4; ++r) {
        float s = s_part[r];
        s += __shfl_xor(s, 1);
        s += __shfl_xor(s, 2);
        s += __shfl_xor(s, 4);
        s += __shfl_xor(s, 8);
        s_part[r] = 1.0f / s;
    }
#pragma unroll
    for (int nd = 0; nd < 4; ++nd) {
        int c = h * 64 + nd * 16 + il;
#pragma unroll
        for (int r = 0; r < 4; ++r) {
            int i = ib * 64 + w * 16 + q * 4 + r;
            Om[((size_t)b_ * 2048 + i) * 512 + c] = (short)f2bf(acc[nd][r] * s_part[r]);
        }
    }
}

// ---------------------------------------------------------------------------
// Output projections (+bias), fp32 out. z=0: out, z=1: context_out.
// ---------------------------------------------------------------------------
__global__ __launch_bounds__(256) void final_kernel(
    const short* __restrict__ OUTx, const short* __restrict__ OUTc,
    const short* __restrict__ wT,
    const float* __restrict__ b_out, const float* __restrict__ b_cout,
    float* __restrict__ dout)
{
    int z = blockIdx.z;
    const short* Am = z ? OUTc : OUTx;
    const short* w = wT + (size_t)(4 + z) * 512 * 512;
    const float* bias = z ? b_cout : b_out;
    float* D = dout + (size_t)z * 4096 * 512;
    int wid = threadIdx.x >> 6, lane = threadIdx.x & 63, il = lane & 15, q = lane >> 4;
    int mb = blockIdx.x * 64 + wid * 16;
    int nb = blockIdx.y * 64;
    const short* arow = Am + (size_t)(mb + il) * 512 + q * 8;
    f32x4 acc[4] = {};
    for (int kk = 0; kk < 16; ++kk) {
        short8 a = *(const short8*)(arow + kk * 32);
#pragma unroll
        for (int nj = 0; nj < 4; ++nj) {
            short8 b = *(const short8*)(w + (size_t)(nb + nj * 16 + il) * 512 + kk * 32 + q * 8);
            acc[nj] = mfma16(a, b, acc[nj]);
        }
    }
#pragma unroll
    for (int nj = 0; nj < 4; ++nj) {
        int c = nb + nj * 16 + il;
        float bi = bias[c];
#pragma unroll
        for (int r = 0; r < 4; ++r) {
            int m = mb + q * 4 + r;
            D[(size_t)m * 512 + c] = acc[nj][r] + bi;
        }
    }
}

// ---------------------------------------------------------------------------
extern "C" void kernel_launch(void* const* d_in, const int* in_sizes, int n_in,
                              void* d_out, int out_size, void* d_ws, size_t ws_size,
                              hipStream_t stream)
{
    (void)in_sizes; (void)n_in; (void)out_size; (void)ws_size;
    const float* x      = (const float*)d_in[0];
    const float* ctx    = (const float*)d_in[1];
    const float* w_qk   = (const float*)d_in[2];
    const float* w_cqk  = (const float*)d_in[3];
    const float* w_v    = (const float*)d_in[4];
    const float* w_cv   = (const float*)d_in[5];
    const float* w_out  = (const float*)d_in[6];
    const float* b_out  = (const float*)d_in[7];
    const float* w_cout = (const float*)d_in[8];
    const float* b_cout = (const float*)d_in[9];
    float* dout = (float*)d_out;

    char* ws = (char*)d_ws;
    const size_t WSZ = (size_t)512 * 512 * 2;       // one bf16 weight matrix
    const size_t TSZ = (size_t)16 * 2048 * 64 * 2;  // one head-split bf16 tensor (4 MB)
    short* wT   = (short*)ws;                        // 6 * WSZ
    short* QK   = (short*)(ws + 6 * WSZ);
    short* CQK  = (short*)(ws + 6 * WSZ + 1 * TSZ);
    short* VT   = (short*)(ws + 6 * WSZ + 2 * TSZ);
    short* CVT  = (short*)(ws + 6 * WSZ + 3 * TSZ);
    short* OUTx = (short*)(ws + 6 * WSZ + 4 * TSZ);
    short* OUTc = (short*)(ws + 6 * WSZ + 5 * TSZ);  // total ~28.3 MB

    trans_kernel<<<dim3(8, 8, 6), 256, 0, stream>>>(w_qk, w_cqk, w_v, w_cv, w_out, w_cout, wT);
    proj_kernel<<<dim3(64, 8, 4), 256, 0, stream>>>(x, ctx, wT, QK, CQK, VT, CVT);
    attn_kernel<<<dim3(16, 32), 256, 0, stream>>>(QK, CQK, CVT, OUTx);   // row softmax -> out
    attn_kernel<<<dim3(16, 32), 256, 0, stream>>>(CQK, QK, VT, OUTc);    // col softmax -> context_out
    final_kernel<<<dim3(64, 8, 2), 256, 0, stream>>>(OUTx, OUTc, wT, b_out, b_cout, dout);
}

// Round 2
// 440.110 us; speedup vs baseline: 1.0018x; 1.0018x over previous
//
#include <hip/hip_runtime.h>

#define DEVI __device__ __forceinline__

typedef __attribute__((ext_vector_type(8))) short short8;
typedef __attribute__((ext_vector_type(4))) float f32x4;

struct alignas(8) us4 { unsigned short a, b, c, d; };

DEVI unsigned short f2bf(float f) {
    unsigned int u = __float_as_uint(f);
    u += 0x7fffU + ((u >> 16) & 1U);   // round-to-nearest-even
    return (unsigned short)(u >> 16);
}

DEVI f32x4 mfma16(short8 a, short8 b, f32x4 c) {
    return __builtin_amdgcn_mfma_f32_16x16x32_bf16(a, b, c, 0, 0, 0);
}

// ---------------------------------------------------------------------------
// Weight transpose + bf16 convert: wT[n][k] = (bf16) w[k][n], 512x512, z = 0..5
// ---------------------------------------------------------------------------
__global__ __launch_bounds__(256) void trans_kernel(
    const float* w0, const float* w1, const float* w2, const float* w3,
    const float* w4, const float* w5, short* wT)
{
    const float* srcs[6] = {w0, w1, w2, w3, w4, w5};
    const float* src = srcs[blockIdx.z];
    short* dst = wT + (size_t)blockIdx.z * 512 * 512;
    int k0 = blockIdx.x * 64, n0 = blockIdx.y * 64;
    __shared__ float tile[64][65];
    int t = threadIdx.x;
    int r = t >> 2, c0 = (t & 3) * 16;
#pragma unroll
    for (int ii = 0; ii < 4; ++ii) {
        float4 v = *(const float4*)(src + (size_t)(k0 + r) * 512 + n0 + c0 + ii * 4);
        tile[r][c0 + ii * 4 + 0] = v.x;
        tile[r][c0 + ii * 4 + 1] = v.y;
        tile[r][c0 + ii * 4 + 2] = v.z;
        tile[r][c0 + ii * 4 + 3] = v.w;
    }
    __syncthreads();
#pragma unroll
    for (int ii = 0; ii < 4; ++ii) {
        us4 o;
        o.a = f2bf(tile[c0 + ii * 4 + 0][r]);
        o.b = f2bf(tile[c0 + ii * 4 + 1][r]);
        o.c = f2bf(tile[c0 + ii * 4 + 2][r]);
        o.d = f2bf(tile[c0 + ii * 4 + 3][r]);
        *(us4*)(dst + (size_t)(n0 + r) * 512 + k0 + c0 + ii * 4) = o;
    }
}

// ---------------------------------------------------------------------------
// Input projections: z=0: QK=x@w_qk (natural [bh][i][d])
//                    z=1: CQK=ctx@w_cqk (natural)
//                    z=2: VT=x@w_v (transposed [bh][d][i])
//                    z=3: CVT=ctx@w_cv (transposed)
// ---------------------------------------------------------------------------
__global__ __launch_bounds__(256) void proj_kernel(
    const float* __restrict__ x, const float* __restrict__ ctx,
    const short* __restrict__ wT,
    short* __restrict__ QK, short* __restrict__ CQK,
    short* __restrict__ VT, short* __restrict__ CVT)
{
    int p = blockIdx.z;
    const float* src = (p == 0 || p == 2) ? x : ctx;
    const short* w = wT + (size_t)p * 512 * 512;
    int wid = threadIdx.x >> 6, lane = threadIdx.x & 63, il = lane & 15, q = lane >> 4;
    int mb = blockIdx.x * 64 + wid * 16;
    int nb = blockIdx.y * 64;
    const float* arow = src + (size_t)(mb + il) * 512 + q * 8;
    f32x4 acc[4] = {};
    for (int kk = 0; kk < 16; ++kk) {
        float4 fa = *(const float4*)(arow + kk * 32);
        float4 fb = *(const float4*)(arow + kk * 32 + 4);
        short8 a;
        a[0] = (short)f2bf(fa.x); a[1] = (short)f2bf(fa.y);
        a[2] = (short)f2bf(fa.z); a[3] = (short)f2bf(fa.w);
        a[4] = (short)f2bf(fb.x); a[5] = (short)f2bf(fb.y);
        a[6] = (short)f2bf(fb.z); a[7] = (short)f2bf(fb.w);
#pragma unroll
        for (int nj = 0; nj < 4; ++nj) {
            short8 b = *(const short8*)(w + (size_t)(nb + nj * 16 + il) * 512 + kk * 32 + q * 8);
            acc[nj] = mfma16(a, b, acc[nj]);
        }
    }
    if (p < 2) {
        short* dst = (p == 0) ? QK : CQK;
#pragma unroll
        for (int nj = 0; nj < 4; ++nj) {
            int c = nb + nj * 16 + il;
            int h = c >> 6, d = c & 63;
#pragma unroll
            for (int r = 0; r < 4; ++r) {
                int m = mb + q * 4 + r;
                int b_ = m >> 11, i = m & 2047;
                dst[(((size_t)b_ * 8 + h) * 2048 + i) * 64 + d] = (short)f2bf(acc[nj][r]);
            }
        }
    } else {
        short* dst = (p == 2) ? VT : CVT;
#pragma unroll
        for (int nj = 0; nj < 4; ++nj) {
            int c = nb + nj * 16 + il;
            int h = c >> 6, d = c & 63;
            int m0 = mb + q * 4;
            int b_ = m0 >> 11, i0 = m0 & 2047;
            us4 o;
            o.a = f2bf(acc[nj][0]); o.b = f2bf(acc[nj][1]);
            o.c = f2bf(acc[nj][2]); o.d = f2bf(acc[nj][3]);
            *(us4*)(dst + (((size_t)b_ * 8 + h) * 64 + d) * 2048 + i0) = o;
        }
    }
}

// ---------------------------------------------------------------------------
// Fused attention, both softmax directions in one launch (blockIdx.z).
// Block: 16 output rows; 4 waves = 4 disjoint 512-wide j-chunks, each wave
// accumulates unnormalized sum_j exp(sim)*W and sum_j exp(sim); LDS combine.
// No max-subtraction needed: |sim*scale| <= ~1.5, exp2 in fp32 is safe.
// ---------------------------------------------------------------------------
__global__ __launch_bounds__(256, 8) void attn_kernel(
    const short* __restrict__ QK, const short* __restrict__ CQK,
    const short* __restrict__ VT, const short* __restrict__ CVT,
    short* __restrict__ OUTx, short* __restrict__ OUTc)
{
    // p_lds[2][4][16][72] shorts (18432 B) unioned with
    // cacc[4][16][68] floats (17408 B) + cs[64] floats (256 B)
    __shared__ __align__(16) char smem[18688];
    short (*p_lds)[4][16][72] = (short (*)[4][16][72])smem;
    float (*cacc)[16][68]     = (float (*)[16][68])smem;
    float* cs                 = (float*)(smem + 17408);

    int z = blockIdx.z;
    const short* Arows = z ? CQK : QK;
    const short* Bcols = z ? QK  : CQK;
    const short* WT    = z ? VT  : CVT;
    short* Om          = z ? OUTc : OUTx;

    int bh = blockIdx.x, ib = blockIdx.y;
    int b_ = bh >> 3, h = bh & 7;
    int w = threadIdx.x >> 6, lane = threadIdx.x & 63, il = lane & 15, q = lane >> 4;
    const short* Ab = Arows + (size_t)bh * 2048 * 64;
    const short* Bb = Bcols + (size_t)bh * 2048 * 64;
    const short* Wb = WT + (size_t)bh * 64 * 2048;

    int i_row = ib * 16 + il;
    short8 aq0 = *(const short8*)(Ab + (size_t)i_row * 64 + q * 8);
    short8 aq1 = *(const short8*)(Ab + (size_t)i_row * 64 + 32 + q * 8);

    f32x4 acc[4] = {};
    float s_part[4] = {0.f, 0.f, 0.f, 0.f};
    const float C = 0.18033688011112042f;  // log2(e) / 8  (folds SCALE into exp2)

    for (int jt = 0; jt < 8; ++jt) {
        int j0 = w * 512 + jt * 64;
        int pb = jt & 1;
        f32x4 sim[4];
#pragma unroll
        for (int nj = 0; nj < 4; ++nj) {
            const short* bp = Bb + (size_t)(j0 + nj * 16 + il) * 64 + q * 8;
            short8 b0 = *(const short8*)(bp);
            short8 b1 = *(const short8*)(bp + 32);
            f32x4 zz = {};
            zz = mfma16(aq0, b0, zz);
            sim[nj] = mfma16(aq1, b1, zz);
        }
#pragma unroll
        for (int nj = 0; nj < 4; ++nj) {
#pragma unroll
            for (int r = 0; r < 4; ++r) {
                float pv = __builtin_amdgcn_exp2f(sim[nj][r] * C);
                s_part[r] += pv;
                p_lds[pb][w][q * 4 + r][nj * 16 + il] = (short)f2bf(pv);
            }
        }
        short8 pa0 = *(const short8*)(&p_lds[pb][w][il][q * 8]);
        short8 pa1 = *(const short8*)(&p_lds[pb][w][il][32 + q * 8]);
#pragma unroll
        for (int nd = 0; nd < 4; ++nd) {
            const short* vp = Wb + (size_t)(nd * 16 + il) * 2048 + j0 + q * 8;
            short8 v0 = *(const short8*)(vp);
            short8 v1 = *(const short8*)(vp + 32);
            acc[nd] = mfma16(pa0, v0, acc[nd]);
            acc[nd] = mfma16(pa1, v1, acc[nd]);
        }
    }

    // reduce s over the 16 il-lanes (rows live at (q, r))
#pragma unroll
    for (int r = 0; r < 4; ++r) {
        float s = s_part[r];
        s += __shfl_xor(s, 1);
        s += __shfl_xor(s, 2);
        s += __shfl_xor(s, 4);
        s += __shfl_xor(s, 8);
        s_part[r] = s;
    }

    __syncthreads();  // everyone done with p_lds before combine buffers overwrite it
#pragma unroll
    for (int nd = 0; nd < 4; ++nd)
#pragma unroll
        for (int r = 0; r < 4; ++r)
            cacc[w][q * 4 + r][nd * 16 + il] = acc[nd][r];
    if (il == 0) {
#pragma unroll
        for (int r = 0; r < 4; ++r) cs[w * 16 + q * 4 + r] = s_part[r];
    }
    __syncthreads();

    // combine the 4 j-chunk partials and write bf16 output
    int t = threadIdx.x;
    int c = t & 63, rbase = (t >> 6) * 4;
#pragma unroll
    for (int rr = 0; rr < 4; ++rr) {
        int r = rbase + rr;
        float v = cacc[0][r][c] + cacc[1][r][c] + cacc[2][r][c] + cacc[3][r][c];
        float s = cs[0 + r] + cs[16 + r] + cs[32 + r] + cs[48 + r];
        Om[((size_t)b_ * 2048 + ib * 16 + r) * 512 + h * 64 + c] = (short)f2bf(v / s);
    }
}

// ---------------------------------------------------------------------------
// Output projections (+bias), fp32 out. z=0: out, z=1: context_out.
// ---------------------------------------------------------------------------
__global__ __launch_bounds__(256) void final_kernel(
    const short* __restrict__ OUTx, const short* __restrict__ OUTc,
    const short* __restrict__ wT,
    const float* __restrict__ b_out, const float* __restrict__ b_cout,
    float* __restrict__ dout)
{
    int z = blockIdx.z;
    const short* Am = z ? OUTc : OUTx;
    const short* w = wT + (size_t)(4 + z) * 512 * 512;
    const float* bias = z ? b_cout : b_out;
    float* D = dout + (size_t)z * 4096 * 512;
    int wid = threadIdx.x >> 6, lane = threadIdx.x & 63, il = lane & 15, q = lane >> 4;
    int mb = blockIdx.x * 64 + wid * 16;
    int nb = blockIdx.y * 64;
    const short* arow = Am + (size_t)(mb + il) * 512 + q * 8;
    f32x4 acc[4] = {};
    for (int kk = 0; kk < 16; ++kk) {
        short8 a = *(const short8*)(arow + kk * 32);
#pragma unroll
        for (int nj = 0; nj < 4; ++nj) {
            short8 b = *(const short8*)(w + (size_t)(nb + nj * 16 + il) * 512 + kk * 32 + q * 8);
            acc[nj] = mfma16(a, b, acc[nj]);
        }
    }
#pragma unroll
    for (int nj = 0; nj < 4; ++nj) {
        int c = nb + nj * 16 + il;
        float bi = bias[c];
#pragma unroll
        for (int r = 0; r < 4; ++r) {
            int m = mb + q * 4 + r;
            D[(size_t)m * 512 + c] = acc[nj][r] + bi;
        }
    }
}

// ---------------------------------------------------------------------------
extern "C" void kernel_launch(void* const* d_in, const int* in_sizes, int n_in,
                              void* d_out, int out_size, void* d_ws, size_t ws_size,
                              hipStream_t stream)
{
    (void)in_sizes; (void)n_in; (void)out_size; (void)ws_size;
    const float* x      = (const float*)d_in[0];
    const float* ctx    = (const float*)d_in[1];
    const float* w_qk   = (const float*)d_in[2];
    const float* w_cqk  = (const float*)d_in[3];
    const float* w_v    = (const float*)d_in[4];
    const float* w_cv   = (const float*)d_in[5];
    const float* w_out  = (const float*)d_in[6];
    const float* b_out  = (const float*)d_in[7];
    const float* w_cout = (const float*)d_in[8];
    const float* b_cout = (const float*)d_in[9];
    float* dout = (float*)d_out;

    char* ws = (char*)d_ws;
    const size_t WSZ = (size_t)512 * 512 * 2;       // one bf16 weight matrix
    const size_t TSZ = (size_t)16 * 2048 * 64 * 2;  // one head-split bf16 tensor (4 MB)
    short* wT   = (short*)ws;                        // 6 * WSZ
    short* QK   = (short*)(ws + 6 * WSZ);
    short* CQK  = (short*)(ws + 6 * WSZ + 1 * TSZ);
    short* VT   = (short*)(ws + 6 * WSZ + 2 * TSZ);
    short* CVT  = (short*)(ws + 6 * WSZ + 3 * TSZ);
    short* OUTx = (short*)(ws + 6 * WSZ + 4 * TSZ);
    short* OUTc = (short*)(ws + 6 * WSZ + 5 * TSZ);  // total ~28.3 MB

    trans_kernel<<<dim3(8, 8, 6), 256, 0, stream>>>(w_qk, w_cqk, w_v, w_cv, w_out, w_cout, wT);
    proj_kernel<<<dim3(64, 8, 4), 256, 0, stream>>>(x, ctx, wT, QK, CQK, VT, CVT);
    attn_kernel<<<dim3(16, 128, 2), 256, 0, stream>>>(QK, CQK, VT, CVT, OUTx, OUTc);
    final_kernel<<<dim3(64, 8, 2), 256, 0, stream>>>(OUTx, OUTc, wT, b_out, b_cout, dout);
}

// Round 3
// 180.114 us; speedup vs baseline: 2.4479x; 2.4435x over previous
//
#include <hip/hip_runtime.h>

#define DEVI __device__ __forceinline__

typedef __attribute__((ext_vector_type(8))) short short8;
typedef __attribute__((ext_vector_type(4))) float f32x4;

struct alignas(8) us4 { unsigned short a, b, c, d; };

DEVI unsigned short f2bf(float f) {
    unsigned int u = __float_as_uint(f);
    u += 0x7fffU + ((u >> 16) & 1U);   // round-to-nearest-even
    return (unsigned short)(u >> 16);
}

DEVI f32x4 mfma16(short8 a, short8 b, f32x4 c) {
    return __builtin_amdgcn_mfma_f32_16x16x32_bf16(a, b, c, 0, 0, 0);
}

// global_load_lds: 16B per lane, LDS dest = wave-uniform base + lane*16 (linear).
#define GLDS(gp, sp) __builtin_amdgcn_global_load_lds( \
    (const __attribute__((address_space(1))) void*)(gp), \
    (__attribute__((address_space(3))) void*)(sp), 16, 0, 0)

// ---------------------------------------------------------------------------
// x/ctx fp32 -> bf16 (for proj A-operand)
// ---------------------------------------------------------------------------
__global__ __launch_bounds__(256) void xcvt_kernel(
    const float* __restrict__ x, const float* __restrict__ ctx,
    short* __restrict__ Xb, short* __restrict__ Cb)
{
    const float* s = blockIdx.z ? ctx : x;
    short* d = blockIdx.z ? Cb : Xb;
    size_t t = (size_t)blockIdx.x * 256 + threadIdx.x;
    float4 v = *(const float4*)(s + t * 4);
    us4 o = { f2bf(v.x), f2bf(v.y), f2bf(v.z), f2bf(v.w) };
    *(us4*)(d + t * 4) = o;
}

// ---------------------------------------------------------------------------
// Weight transpose + bf16 convert: wT[n][k] = (bf16) w[k][n], 512x512, z = 0..5
// ---------------------------------------------------------------------------
__global__ __launch_bounds__(256) void trans_kernel(
    const float* w0, const float* w1, const float* w2, const float* w3,
    const float* w4, const float* w5, short* wT)
{
    const float* srcs[6] = {w0, w1, w2, w3, w4, w5};
    const float* src = srcs[blockIdx.z];
    short* dst = wT + (size_t)blockIdx.z * 512 * 512;
    int k0 = blockIdx.x * 64, n0 = blockIdx.y * 64;
    __shared__ float tile[64][65];
    int t = threadIdx.x;
    int r = t >> 2, c0 = (t & 3) * 16;
#pragma unroll
    for (int ii = 0; ii < 4; ++ii) {
        float4 v = *(const float4*)(src + (size_t)(k0 + r) * 512 + n0 + c0 + ii * 4);
        tile[r][c0 + ii * 4 + 0] = v.x;
        tile[r][c0 + ii * 4 + 1] = v.y;
        tile[r][c0 + ii * 4 + 2] = v.z;
        tile[r][c0 + ii * 4 + 3] = v.w;
    }
    __syncthreads();
#pragma unroll
    for (int ii = 0; ii < 4; ++ii) {
        us4 o;
        o.a = f2bf(tile[c0 + ii * 4 + 0][r]);
        o.b = f2bf(tile[c0 + ii * 4 + 1][r]);
        o.c = f2bf(tile[c0 + ii * 4 + 2][r]);
        o.d = f2bf(tile[c0 + ii * 4 + 3][r]);
        *(us4*)(dst + (size_t)(n0 + r) * 512 + k0 + c0 + ii * 4) = o;
    }
}

// ---------------------------------------------------------------------------
// Input projections. A = bf16 x/ctx. W chunks staged in LDS (swizzled, shared
// by all 4 waves). C-tile goes through LDS for coalesced layout-specific
// stores: p<2 -> [bh][i][d] (128B rows), p>=2 -> [bh][d][i] (32B segments).
// ---------------------------------------------------------------------------
__global__ __launch_bounds__(256, 4) void proj_kernel(
    const short* __restrict__ Xb, const short* __restrict__ Cb,
    const short* __restrict__ wT,
    short* __restrict__ QK, short* __restrict__ CQK,
    short* __restrict__ VT, short* __restrict__ CVT)
{
    __shared__ short wst[4096];        // [64 n][8 slot] swizzled (8KB)
    __shared__ float ctile[64][69];
    int p = blockIdx.z;
    const short* src = (p & 1) ? Cb : Xb;
    const short* w = wT + (size_t)p * 262144;
    int wid = threadIdx.x >> 6, lane = threadIdx.x & 63, il = lane & 15, q = lane >> 4;
    int mb = blockIdx.x * 64, nb = blockIdx.y * 64;
    int srow = lane >> 3;
    int scol8 = ((lane & 7) ^ srow) * 8;
    const short* arow = src + (size_t)(mb + wid * 16 + il) * 512;
    f32x4 acc[4] = {};
    for (int ck = 0; ck < 8; ++ck) {
        int k0 = ck * 64;
        __syncthreads();
        GLDS(w + (size_t)(nb + wid * 16 + srow) * 512 + k0 + scol8, wst + wid * 1024);
        GLDS(w + (size_t)(nb + wid * 16 + 8 + srow) * 512 + k0 + scol8, wst + wid * 1024 + 512);
        asm volatile("s_waitcnt vmcnt(0)" ::: "memory");
        __syncthreads();
#pragma unroll
        for (int kk = 0; kk < 2; ++kk) {
            short8 a = *(const short8*)(arow + k0 + kk * 32 + q * 8);
#pragma unroll
            for (int nj = 0; nj < 4; ++nj) {
                short8 b = *(const short8*)(wst + (nj * 16 + il) * 64 + ((((kk << 2) + q) ^ (il & 7)) << 3));
                acc[nj] = mfma16(a, b, acc[nj]);
            }
        }
    }
    __syncthreads();
#pragma unroll
    for (int nj = 0; nj < 4; ++nj)
#pragma unroll
        for (int r = 0; r < 4; ++r)
            ctile[wid * 16 + q * 4 + r][nj * 16 + il] = acc[nj][r];
    __syncthreads();
    int t = threadIdx.x, row = t >> 2, seg = (t & 3) * 16;
    short tmp[16];
    int h = blockIdx.y;
    if (p < 2) {
        short* dst = p ? CQK : QK;
        int i = mb + row, b2 = i >> 11, iL = i & 2047;
#pragma unroll
        for (int e = 0; e < 16; ++e) tmp[e] = (short)f2bf(ctile[row][seg + e]);
        short* dp = dst + (((size_t)b2 * 8 + h) * 2048 + iL) * 64 + seg;
        *(short8*)dp = *(const short8*)tmp;
        *(short8*)(dp + 8) = *(const short8*)(tmp + 8);
    } else {
        short* dst = (p == 2) ? VT : CVT;
        int d = row;
        int i0 = mb + seg, b2 = i0 >> 11, iL = i0 & 2047;
#pragma unroll
        for (int e = 0; e < 16; ++e) tmp[e] = (short)f2bf(ctile[seg + e][d]);
        short* dp = dst + (((size_t)b2 * 8 + h) * 64 + d) * 2048 + iL;
        *(short8*)dp = *(const short8*)tmp;
        *(short8*)(dp + 8) = *(const short8*)(tmp + 8);
    }
}

// ---------------------------------------------------------------------------
// Fused attention, both directions (blockIdx.z). 128 rows/block, 8 waves x 16
// rows, full-j sweep per wave. B/W tiles LDS-staged via global_load_lds with
// pre-swizzled source (XOR slot^row&7), double-buffered, counted vmcnt.
// ---------------------------------------------------------------------------
__global__ __launch_bounds__(512, 4) void attn_kernel(
    const short* __restrict__ QK, const short* __restrict__ CQK,
    const short* __restrict__ VT, const short* __restrict__ CVT,
    short* __restrict__ OUTx, short* __restrict__ OUTc)
{
    __shared__ short At[8192];       // [128][8 slot] swizzled, 16KB
    __shared__ short Bt[2][4096];    // [64 j][8 slot] swizzled, 2 x 8KB
    __shared__ short Wt[2][4096];    // [64 d][8 slot] swizzled, 2 x 8KB
    __shared__ short p_lds[8][16][72];

    int z = blockIdx.z;
    const short* Arows = z ? CQK : QK;
    const short* Bcols = z ? QK : CQK;
    const short* WTm   = z ? VT : CVT;
    short* Om          = z ? OUTc : OUTx;

    int bh = blockIdx.x, ib = blockIdx.y;
    int b_ = bh >> 3, h = bh & 7;
    int w = threadIdx.x >> 6, lane = threadIdx.x & 63, il = lane & 15, q = lane >> 4;
    const short* Ab = Arows + (size_t)bh * 131072;
    const short* Bb = Bcols + (size_t)bh * 131072;
    const short* Wb = WTm + (size_t)bh * 131072;

    int srow = lane >> 3;
    int scol8 = ((lane & 7) ^ srow) * 8;
    int isW = (w >= 4);
    int ws = w & 3;
    int key = (il & 7);

#define STAGE(buf, j0v) do { \
        int r0_ = ws * 16 + srow; \
        if (!isW) { \
            GLDS(Bb + (size_t)((j0v) + r0_) * 64 + scol8, Bt[buf] + ws * 1024); \
            GLDS(Bb + (size_t)((j0v) + r0_ + 8) * 64 + scol8, Bt[buf] + ws * 1024 + 512); \
        } else { \
            GLDS(Wb + (size_t)r0_ * 2048 + (j0v) + scol8, Wt[buf] + ws * 1024); \
            GLDS(Wb + (size_t)(r0_ + 8) * 2048 + (j0v) + scol8, Wt[buf] + ws * 1024 + 512); \
        } } while (0)

    // prologue: stage this wave's 16 A-rows + tile 0
    GLDS(Ab + (size_t)(ib * 128 + w * 16 + srow) * 64 + scol8, At + w * 1024);
    GLDS(Ab + (size_t)(ib * 128 + w * 16 + 8 + srow) * 64 + scol8, At + w * 1024 + 512);
    STAGE(0, 0);
    asm volatile("s_waitcnt vmcnt(2)" ::: "memory");  // A done (own-wave data)

    short8 aq0 = *(const short8*)(At + (w * 16 + il) * 64 + ((q ^ key) << 3));
    short8 aq1 = *(const short8*)(At + (w * 16 + il) * 64 + (((q + 4) ^ key) << 3));

    f32x4 acc[4] = {};
    float s_part[4] = {0.f, 0.f, 0.f, 0.f};
    const float C = 0.18033688011112042f;  // log2(e) / 8

    for (int jt = 0; jt < 32; ++jt) {
        int cur = jt & 1;
        if (jt < 31) {
            STAGE(cur ^ 1, (jt + 1) * 64);
            asm volatile("s_waitcnt vmcnt(2)" ::: "memory");
        } else {
            asm volatile("s_waitcnt vmcnt(0)" ::: "memory");
        }
        __builtin_amdgcn_s_barrier();

        f32x4 sim[4];
#pragma unroll
        for (int nj = 0; nj < 4; ++nj) {
            const short* bb = Bt[cur] + (nj * 16 + il) * 64;
            short8 b0 = *(const short8*)(bb + ((q ^ key) << 3));
            short8 b1 = *(const short8*)(bb + (((q + 4) ^ key) << 3));
            f32x4 zz = {};
            zz = mfma16(aq0, b0, zz);
            sim[nj] = mfma16(aq1, b1, zz);
        }
#pragma unroll
        for (int nj = 0; nj < 4; ++nj) {
#pragma unroll
            for (int r = 0; r < 4; ++r) {
                float pv = __builtin_amdgcn_exp2f(sim[nj][r] * C);
                s_part[r] += pv;
                p_lds[w][q * 4 + r][nj * 16 + il] = (short)f2bf(pv);
            }
        }
        short8 pa0 = *(const short8*)(&p_lds[w][il][q * 8]);
        short8 pa1 = *(const short8*)(&p_lds[w][il][32 + q * 8]);
#pragma unroll
        for (int nd = 0; nd < 4; ++nd) {
            const short* vv = Wt[cur] + (nd * 16 + il) * 64;
            short8 v0 = *(const short8*)(vv + ((q ^ key) << 3));
            short8 v1 = *(const short8*)(vv + (((q + 4) ^ key) << 3));
            acc[nd] = mfma16(pa0, v0, acc[nd]);
            acc[nd] = mfma16(pa1, v1, acc[nd]);
        }
        asm volatile("" ::: "memory");
        __builtin_amdgcn_s_barrier();
    }
#undef STAGE

#pragma unroll
    for (int r = 0; r < 4; ++r) {
        float s = s_part[r];
        s += __shfl_xor(s, 1);
        s += __shfl_xor(s, 2);
        s += __shfl_xor(s, 4);
        s += __shfl_xor(s, 8);
        s_part[r] = 1.0f / s;
    }
#pragma unroll
    for (int nd = 0; nd < 4; ++nd) {
        int c = h * 64 + nd * 16 + il;
#pragma unroll
        for (int r = 0; r < 4; ++r) {
            int i = ib * 128 + w * 16 + q * 4 + r;
            Om[((size_t)b_ * 2048 + i) * 512 + c] = (short)f2bf(acc[nd][r] * s_part[r]);
        }
    }
}

// ---------------------------------------------------------------------------
// Output projections (+bias), fp32 out. W chunks staged in LDS.
// ---------------------------------------------------------------------------
__global__ __launch_bounds__(256, 4) void final_kernel(
    const short* __restrict__ OUTx, const short* __restrict__ OUTc,
    const short* __restrict__ wT,
    const float* __restrict__ b_out, const float* __restrict__ b_cout,
    float* __restrict__ dout)
{
    __shared__ short wst[4096];
    int z = blockIdx.z;
    const short* Am = z ? OUTc : OUTx;
    const short* w = wT + (size_t)(4 + z) * 262144;
    const float* bias = z ? b_cout : b_out;
    float* D = dout + (size_t)z * 2097152;
    int wid = threadIdx.x >> 6, lane = threadIdx.x & 63, il = lane & 15, q = lane >> 4;
    int mb = blockIdx.x * 64, nb = blockIdx.y * 64;
    int srow = lane >> 3;
    int scol8 = ((lane & 7) ^ srow) * 8;
    const short* arow = Am + (size_t)(mb + wid * 16 + il) * 512;
    f32x4 acc[4] = {};
    for (int ck = 0; ck < 8; ++ck) {
        int k0 = ck * 64;
        __syncthreads();
        GLDS(w + (size_t)(nb + wid * 16 + srow) * 512 + k0 + scol8, wst + wid * 1024);
        GLDS(w + (size_t)(nb + wid * 16 + 8 + srow) * 512 + k0 + scol8, wst + wid * 1024 + 512);
        asm volatile("s_waitcnt vmcnt(0)" ::: "memory");
        __syncthreads();
#pragma unroll
        for (int kk = 0; kk < 2; ++kk) {
            short8 a = *(const short8*)(arow + k0 + kk * 32 + q * 8);
#pragma unroll
            for (int nj = 0; nj < 4; ++nj) {
                short8 b = *(const short8*)(wst + (nj * 16 + il) * 64 + ((((kk << 2) + q) ^ (il & 7)) << 3));
                acc[nj] = mfma16(a, b, acc[nj]);
            }
        }
    }
#pragma unroll
    for (int nj = 0; nj < 4; ++nj) {
        int c = nb + nj * 16 + il;
        float bi = bias[c];
#pragma unroll
        for (int r = 0; r < 4; ++r) {
            int m = mb + wid * 16 + q * 4 + r;
            D[(size_t)m * 512 + c] = acc[nj][r] + bi;
        }
    }
}

// ---------------------------------------------------------------------------
extern "C" void kernel_launch(void* const* d_in, const int* in_sizes, int n_in,
                              void* d_out, int out_size, void* d_ws, size_t ws_size,
                              hipStream_t stream)
{
    (void)in_sizes; (void)n_in; (void)out_size; (void)ws_size;
    const float* x      = (const float*)d_in[0];
    const float* ctx    = (const float*)d_in[1];
    const float* w_qk   = (const float*)d_in[2];
    const float* w_cqk  = (const float*)d_in[3];
    const float* w_v    = (const float*)d_in[4];
    const float* w_cv   = (const float*)d_in[5];
    const float* w_out  = (const float*)d_in[6];
    const float* b_out  = (const float*)d_in[7];
    const float* w_cout = (const float*)d_in[8];
    const float* b_cout = (const float*)d_in[9];
    float* dout = (float*)d_out;

    char* ws = (char*)d_ws;
    const size_t WSZ = (size_t)512 * 512 * 2;       // one bf16 weight matrix
    const size_t TSZ = (size_t)16 * 2048 * 64 * 2;  // one head-split bf16 tensor (4 MB)
    short* wT   = (short*)ws;                        // 6 * WSZ = 3 MB
    short* Xb   = (short*)(ws + 6 * WSZ);            // also OUTx (aliased, disjoint lifetime)
    short* Cb   = (short*)(ws + 6 * WSZ + 1 * TSZ);  // also OUTc
    short* QK   = (short*)(ws + 6 * WSZ + 2 * TSZ);
    short* CQK  = (short*)(ws + 6 * WSZ + 3 * TSZ);
    short* VT   = (short*)(ws + 6 * WSZ + 4 * TSZ);
    short* CVT  = (short*)(ws + 6 * WSZ + 5 * TSZ);  // total ~27.3 MB
    short* OUTx = Xb;
    short* OUTc = Cb;

    xcvt_kernel<<<dim3(2048, 1, 2), 256, 0, stream>>>(x, ctx, Xb, Cb);
    trans_kernel<<<dim3(8, 8, 6), 256, 0, stream>>>(w_qk, w_cqk, w_v, w_cv, w_out, w_cout, wT);
    proj_kernel<<<dim3(64, 8, 4), 256, 0, stream>>>(Xb, Cb, wT, QK, CQK, VT, CVT);
    attn_kernel<<<dim3(16, 16, 2), 512, 0, stream>>>(QK, CQK, VT, CVT, OUTx, OUTc);
    final_kernel<<<dim3(64, 8, 2), 256, 0, stream>>>(OUTx, OUTc, wT, b_out, b_cout, dout);
}

// Round 5
// 175.152 us; speedup vs baseline: 2.5173x; 1.0283x over previous
//
#include <hip/hip_runtime.h>

#define DEVI __device__ __forceinline__

typedef __attribute__((ext_vector_type(8))) short short8;
typedef __attribute__((ext_vector_type(4))) float f32x4;

struct alignas(8) us4 { unsigned short a, b, c, d; };

DEVI unsigned short f2bf(float f) {
    unsigned int u = __float_as_uint(f);
    u += 0x7fffU + ((u >> 16) & 1U);   // round-to-nearest-even
    return (unsigned short)(u >> 16);
}

DEVI f32x4 mfma16(short8 a, short8 b, f32x4 c) {
    return __builtin_amdgcn_mfma_f32_16x16x32_bf16(a, b, c, 0, 0, 0);
}

DEVI short8 mk8(unsigned a, unsigned b, unsigned c, unsigned d) {
    union { unsigned u[4]; short8 s; } x;
    x.u[0] = a; x.u[1] = b; x.u[2] = c; x.u[3] = d;
    return x.s;
}

// global_load_lds: 16B/lane, LDS dest = wave-uniform base + lane*16 (linear).
#define GLDS(gp, sp) __builtin_amdgcn_global_load_lds( \
    (const __attribute__((address_space(1))) void*)(gp), \
    (__attribute__((address_space(3))) void*)(sp), 16, 0, 0)

#define VMCNT(n) asm volatile("s_waitcnt vmcnt(" #n ")" ::: "memory")

// sqrt(log2(e)/8): pre-scale for QK/CQK so attn does exp2(sim) directly.
#define SQC 0.42466089f

// ---------------------------------------------------------------------------
// prep: z=0/1: x/ctx fp32->bf16; z=2: 6 weight transposes (bf16).
// ---------------------------------------------------------------------------
__global__ __launch_bounds__(256) void prep_kernel(
    const float* __restrict__ x, const float* __restrict__ ctx,
    const float* w0, const float* w1, const float* w2, const float* w3,
    const float* w4, const float* w5,
    short* __restrict__ Xb, short* __restrict__ Cb, short* __restrict__ wT)
{
    int z = blockIdx.z;
    if (z < 2) {
        const float* s = z ? ctx : x;
        short* d = z ? Cb : Xb;
        size_t t = (size_t)blockIdx.x * 256 + threadIdx.x;
        float4 v = *(const float4*)(s + t * 4);
        us4 o = { f2bf(v.x), f2bf(v.y), f2bf(v.z), f2bf(v.w) };
        *(us4*)(d + t * 4) = o;
        return;
    }
    if (blockIdx.x >= 384) return;
    const float* srcs[6] = {w0, w1, w2, w3, w4, w5};
    int wz = blockIdx.x >> 6, rem = blockIdx.x & 63;
    const float* src = srcs[wz];
    short* dst = wT + (size_t)wz * 262144;
    int k0 = (rem >> 3) * 64, n0 = (rem & 7) * 64;
    __shared__ float tile[64][65];
    int t = threadIdx.x;
    int r = t >> 2, c0 = (t & 3) * 16;
#pragma unroll
    for (int ii = 0; ii < 4; ++ii) {
        float4 v = *(const float4*)(src + (size_t)(k0 + r) * 512 + n0 + c0 + ii * 4);
        tile[r][c0 + ii * 4 + 0] = v.x;
        tile[r][c0 + ii * 4 + 1] = v.y;
        tile[r][c0 + ii * 4 + 2] = v.z;
        tile[r][c0 + ii * 4 + 3] = v.w;
    }
    __syncthreads();
#pragma unroll
    for (int ii = 0; ii < 4; ++ii) {
        us4 o;
        o.a = f2bf(tile[c0 + ii * 4 + 0][r]);
        o.b = f2bf(tile[c0 + ii * 4 + 1][r]);
        o.c = f2bf(tile[c0 + ii * 4 + 2][r]);
        o.d = f2bf(tile[c0 + ii * 4 + 3][r]);
        *(us4*)(dst + (size_t)(n0 + r) * 512 + k0 + c0 + ii * 4) = o;
    }
}

// ---------------------------------------------------------------------------
// Input projections. A rows held in registers (16 short8), W double-buffered
// in LDS via global_load_lds + counted vmcnt. p<2 outputs pre-scaled by SQC.
// ---------------------------------------------------------------------------
__global__ __launch_bounds__(256, 4) void proj_kernel(
    const short* __restrict__ Xb, const short* __restrict__ Cb,
    const short* __restrict__ wT,
    short* __restrict__ QK, short* __restrict__ CQK,
    short* __restrict__ VT, short* __restrict__ CVT)
{
    __shared__ __align__(16) char smem[17664];
    short (*wst)[4096] = (short (*)[4096])smem;   // [2][64 rows][8 slots]
    float (*ctile)[69] = (float (*)[69])smem;     // overlaid epilogue buffer

    int p = blockIdx.z;
    const short* src = (p & 1) ? Cb : Xb;
    const short* wm = wT + (size_t)p * 262144;
    int wid = threadIdx.x >> 6, lane = threadIdx.x & 63, il = lane & 15, q = lane >> 4;
    int mb = blockIdx.x * 64, nb = blockIdx.y * 64;
    int srow = lane >> 3, scol8 = ((lane & 7) ^ srow) << 3;
    int key = il & 7;
    const short* wL0 = wm + (size_t)(nb + wid * 16 + srow) * 512 + scol8;
    const short* wL1 = wL0 + 8 * 512;
#define PSTAGE(buf, ck) do { \
    GLDS(wL0 + (ck) * 64, &wst[buf][wid * 1024]); \
    GLDS(wL1 + (ck) * 64, &wst[buf][wid * 1024 + 512]); } while (0)

    PSTAGE(0, 0);
    const short* arow = src + (size_t)(mb + wid * 16 + il) * 512;
    short8 a[16];
#pragma unroll
    for (int j = 0; j < 16; ++j) a[j] = *(const short8*)(arow + j * 32 + (q << 3));

    f32x4 acc[4] = {};
#pragma unroll
    for (int ck = 0; ck < 8; ++ck) {
        int buf = ck & 1;
        if (ck < 7) { PSTAGE(buf ^ 1, ck + 1); VMCNT(2); } else { VMCNT(0); }
        __builtin_amdgcn_s_barrier();
#pragma unroll
        for (int kk = 0; kk < 2; ++kk) {
#pragma unroll
            for (int nj = 0; nj < 4; ++nj) {
                short8 b = *(const short8*)(&wst[buf][(nj * 16 + il) * 64 + ((((kk << 2) + q) ^ key) << 3)]);
                acc[nj] = mfma16(a[ck * 2 + kk], b, acc[nj]);
            }
        }
        asm volatile("" ::: "memory");
        __builtin_amdgcn_s_barrier();
    }
#undef PSTAGE

#pragma unroll
    for (int nj = 0; nj < 4; ++nj)
#pragma unroll
        for (int r = 0; r < 4; ++r)
            ctile[wid * 16 + q * 4 + r][nj * 16 + il] = acc[nj][r];
    __syncthreads();
    int t = threadIdx.x, row = t >> 2, seg = (t & 3) << 4;
    short tmp[16];
    int h = blockIdx.y;
    if (p < 2) {
        short* dst = p ? CQK : QK;
        int i = mb + row, b2 = i >> 11, iL = i & 2047;
#pragma unroll
        for (int e = 0; e < 16; ++e) tmp[e] = (short)f2bf(ctile[row][seg + e] * SQC);
        short* dp = dst + (((size_t)b2 * 8 + h) * 2048 + iL) * 64 + seg;
        *(short8*)dp = *(const short8*)tmp;
        *(short8*)(dp + 8) = *(const short8*)(tmp + 8);
    } else {
        short* dst = (p == 2) ? VT : CVT;
        int d = row;
        int i0 = mb + seg, b2 = i0 >> 11, iL = i0 & 2047;
#pragma unroll
        for (int e = 0; e < 16; ++e) tmp[e] = (short)f2bf(ctile[seg + e][d]);
        short* dp = dst + (((size_t)b2 * 8 + h) * 64 + d) * 2048 + iL;
        *(short8*)dp = *(const short8*)tmp;
        *(short8*)(dp + 8) = *(const short8*)(tmp + 8);
    }
}

// ---------------------------------------------------------------------------
// Fused attention, both directions. 4 waves x 32 rows = 128 rows/block.
// Swapped sim (mfma(K,Q)) + rho-permuted Bt rows => PV A-frag built fully
// in-lane with RNE f2bf pack (no LDS P round-trip, no cvt_pk).
// Denominator: fp32 per-lane accumulation of unrounded P (r3 semantics),
// reduced over q-lanes and redistributed by shuffle in the epilogue.
// ---------------------------------------------------------------------------
__global__ __launch_bounds__(256, 3) void attn_kernel(
    const short* __restrict__ QK, const short* __restrict__ CQK,
    const short* __restrict__ VT, const short* __restrict__ CVT,
    short* __restrict__ OUTx, short* __restrict__ OUTc)
{
    __shared__ __align__(16) short At[8192];     // 128 rows x 64 (16KB)
    __shared__ __align__(16) short Bt[2][4096];  // 64 pos x 64 (2x8KB), rho-permuted rows
    __shared__ __align__(16) short Wt[2][4096];  // 64 d x 64 j (2x8KB)

    int flat = blockIdx.x + (blockIdx.y << 4) + (blockIdx.z << 8);
    int bh = flat & 15;
    int ib = (flat >> 4) & 15;
    int z = flat >> 8;

    const short* Arows = z ? CQK : QK;
    const short* Bcols = z ? QK : CQK;
    const short* WTm   = z ? VT : CVT;
    short* Om          = z ? OUTc : OUTx;

    int b_ = bh >> 3, h = bh & 7;
    int w = threadIdx.x >> 6, lane = threadIdx.x & 63, il = lane & 15, q = lane >> 4;
    const short* Ab = Arows + (size_t)bh * 131072;
    const short* Bb = Bcols + (size_t)bh * 131072;
    const short* Wb = WTm + (size_t)bh * 131072;

    int srow = lane >> 3;
    int scol8 = ((lane & 7) ^ srow) << 3;
    int key = il & 7;

    // Bt row permutation: position p holds source row j(p) with
    // j5=p5, j4=p3, j3=p2, j2=p4, j1=p1, j0=p0  (so lane q's C-frag j's are
    // exactly {q*8+e, 32+q*8+e}).
    int p0 = w * 16 + srow, p1 = p0 + 8;
    int j0p = (p0 & 0x23) | ((p0 & 0x0C) << 1) | ((p0 & 0x10) >> 2);
    int j1p = (p1 & 0x23) | ((p1 & 0x0C) << 1) | ((p1 & 0x10) >> 2);
    const short* BbL0 = Bb + j0p * 64 + scol8;
    const short* BbL1 = Bb + j1p * 64 + scol8;
    const short* WbL0 = Wb + (size_t)p0 * 2048 + scol8;
    const short* WbL1 = WbL0 + 8 * 2048;

#define STAGE(buf, jt) do { \
    GLDS(BbL0 + (jt) * 4096, &Bt[buf][w * 1024]); \
    GLDS(BbL1 + (jt) * 4096, &Bt[buf][w * 1024 + 512]); \
    GLDS(WbL0 + (jt) * 64, &Wt[buf][w * 1024]); \
    GLDS(WbL1 + (jt) * 64, &Wt[buf][w * 1024 + 512]); } while (0)

    // prologue: own 32 A-rows + tile 0
    {
        const short* AbL = Ab + (size_t)(ib * 128 + w * 32 + srow) * 64 + scol8;
        GLDS(AbL, &At[w * 2048]);
        GLDS(AbL + 512, &At[w * 2048 + 512]);
        GLDS(AbL + 1024, &At[w * 2048 + 1024]);
        GLDS(AbL + 1536, &At[w * 2048 + 1536]);
    }
    STAGE(0, 0);
    VMCNT(4);  // own A rows complete

    short8 aq[2][2];
#pragma unroll
    for (int rg = 0; rg < 2; ++rg) {
        const short* base = &At[(w * 32 + rg * 16 + il) * 64];
        aq[rg][0] = *(const short8*)(base + ((q ^ key) << 3));
        aq[rg][1] = *(const short8*)(base + (((q + 4) ^ key) << 3));
    }

    f32x4 acc[2][4] = {};
    float s_acc[2] = {0.f, 0.f};

    for (int jt = 0; jt < 32; ++jt) {
        int cur = jt & 1;
        if (jt < 31) { STAGE(cur ^ 1, jt + 1); VMCNT(4); } else { VMCNT(0); }
        __builtin_amdgcn_s_barrier();

        short8 b0[4], b1[4];
#pragma unroll
        for (int nj = 0; nj < 4; ++nj) {
            const short* bb = &Bt[cur][(nj * 16 + il) * 64];
            b0[nj] = *(const short8*)(bb + ((q ^ key) << 3));
            b1[nj] = *(const short8*)(bb + (((q + 4) ^ key) << 3));
        }

        unsigned pw[2][8];
#pragma unroll
        for (int rg = 0; rg < 2; ++rg) {
#pragma unroll
            for (int nj = 0; nj < 4; ++nj) {
                f32x4 zz = {};
                zz = mfma16(b0[nj], aq[rg][0], zz);
                zz = mfma16(b1[nj], aq[rg][1], zz);
                float e0 = __builtin_amdgcn_exp2f(zz[0]);
                float e1 = __builtin_amdgcn_exp2f(zz[1]);
                float e2 = __builtin_amdgcn_exp2f(zz[2]);
                float e3 = __builtin_amdgcn_exp2f(zz[3]);
                s_acc[rg] += (e0 + e1) + (e2 + e3);
                pw[rg][nj * 2 + 0] = ((unsigned)f2bf(e1) << 16) | (unsigned)f2bf(e0);
                pw[rg][nj * 2 + 1] = ((unsigned)f2bf(e3) << 16) | (unsigned)f2bf(e2);
            }
        }
        short8 pa0[2] = { mk8(pw[0][0], pw[0][1], pw[0][2], pw[0][3]),
                          mk8(pw[1][0], pw[1][1], pw[1][2], pw[1][3]) };
        short8 pa1[2] = { mk8(pw[0][4], pw[0][5], pw[0][6], pw[0][7]),
                          mk8(pw[1][4], pw[1][5], pw[1][6], pw[1][7]) };

#pragma unroll
        for (int nd = 0; nd < 4; ++nd) {
            const short* vv = &Wt[cur][(nd * 16 + il) * 64];
            short8 v0 = *(const short8*)(vv + ((q ^ key) << 3));
            short8 v1 = *(const short8*)(vv + (((q + 4) ^ key) << 3));
#pragma unroll
            for (int rg = 0; rg < 2; ++rg) {
                acc[rg][nd] = mfma16(pa0[rg], v0, acc[rg][nd]);
                acc[rg][nd] = mfma16(pa1[rg], v1, acc[rg][nd]);
            }
        }
        asm volatile("" ::: "memory");
        __builtin_amdgcn_s_barrier();
    }
#undef STAGE

    // Row sums: s_acc[rg] holds this lane's 16-j partial per tile summed over
    // tiles, for query i = il. Reduce over the q-lanes, then shuffle to the
    // output-row layout (row q*4+r lives at source lane q*4+r).
    f32x4 inv[2];
#pragma unroll
    for (int rg = 0; rg < 2; ++rg) {
        float s = s_acc[rg];
        s += __shfl_xor(s, 16);
        s += __shfl_xor(s, 32);
#pragma unroll
        for (int r = 0; r < 4; ++r)
            inv[rg][r] = 1.0f / __shfl(s, q * 4 + r);
    }

#pragma unroll
    for (int rg = 0; rg < 2; ++rg) {
#pragma unroll
        for (int nd = 0; nd < 4; ++nd) {
#pragma unroll
            for (int r = 0; r < 4; ++r) {
                int i = ib * 128 + w * 32 + rg * 16 + q * 4 + r;
                Om[((size_t)b_ * 2048 + i) * 512 + h * 64 + nd * 16 + il] =
                    (short)f2bf(acc[rg][nd][r] * inv[rg][r]);
            }
        }
    }
}

// ---------------------------------------------------------------------------
// Output projections (+bias), fp32 out. A in registers, W double-buffered.
// ---------------------------------------------------------------------------
__global__ __launch_bounds__(256, 4) void final_kernel(
    const short* __restrict__ OUTx, const short* __restrict__ OUTc,
    const short* __restrict__ wT,
    const float* __restrict__ b_out, const float* __restrict__ b_cout,
    float* __restrict__ dout)
{
    __shared__ __align__(16) short wst[2][4096];
    int z = blockIdx.z;
    const short* Am = z ? OUTc : OUTx;
    const short* wm = wT + (size_t)(4 + z) * 262144;
    const float* bias = z ? b_cout : b_out;
    float* D = dout + (size_t)z * 2097152;
    int wid = threadIdx.x >> 6, lane = threadIdx.x & 63, il = lane & 15, q = lane >> 4;
    int mb = blockIdx.x * 64, nb = blockIdx.y * 64;
    int srow = lane >> 3, scol8 = ((lane & 7) ^ srow) << 3;
    int key = il & 7;
    const short* wL0 = wm + (size_t)(nb + wid * 16 + srow) * 512 + scol8;
    const short* wL1 = wL0 + 8 * 512;
#define FSTAGE(buf, ck) do { \
    GLDS(wL0 + (ck) * 64, &wst[buf][wid * 1024]); \
    GLDS(wL1 + (ck) * 64, &wst[buf][wid * 1024 + 512]); } while (0)

    FSTAGE(0, 0);
    const short* arow = Am + (size_t)(mb + wid * 16 + il) * 512;
    short8 a[16];
#pragma unroll
    for (int j = 0; j < 16; ++j) a[j] = *(const short8*)(arow + j * 32 + (q << 3));

    f32x4 acc[4] = {};
#pragma unroll
    for (int ck = 0; ck < 8; ++ck) {
        int buf = ck & 1;
        if (ck < 7) { FSTAGE(buf ^ 1, ck + 1); VMCNT(2); } else { VMCNT(0); }
        __builtin_amdgcn_s_barrier();
#pragma unroll
        for (int kk = 0; kk < 2; ++kk) {
#pragma unroll
            for (int nj = 0; nj < 4; ++nj) {
                short8 b = *(const short8*)(&wst[buf][(nj * 16 + il) * 64 + ((((kk << 2) + q) ^ key) << 3)]);
                acc[nj] = mfma16(a[ck * 2 + kk], b, acc[nj]);
            }
        }
        asm volatile("" ::: "memory");
        __builtin_amdgcn_s_barrier();
    }
#undef FSTAGE

#pragma unroll
    for (int nj = 0; nj < 4; ++nj) {
        int c = nb + nj * 16 + il;
        float bi = bias[c];
#pragma unroll
        for (int r = 0; r < 4; ++r) {
            int m = mb + wid * 16 + q * 4 + r;
            D[(size_t)m * 512 + c] = acc[nj][r] + bi;
        }
    }
}

// ---------------------------------------------------------------------------
extern "C" void kernel_launch(void* const* d_in, const int* in_sizes, int n_in,
                              void* d_out, int out_size, void* d_ws, size_t ws_size,
                              hipStream_t stream)
{
    (void)in_sizes; (void)n_in; (void)out_size; (void)ws_size;
    const float* x      = (const float*)d_in[0];
    const float* ctx    = (const float*)d_in[1];
    const float* w_qk   = (const float*)d_in[2];
    const float* w_cqk  = (const float*)d_in[3];
    const float* w_v    = (const float*)d_in[4];
    const float* w_cv   = (const float*)d_in[5];
    const float* w_out  = (const float*)d_in[6];
    const float* b_out  = (const float*)d_in[7];
    const float* w_cout = (const float*)d_in[8];
    const float* b_cout = (const float*)d_in[9];
    float* dout = (float*)d_out;

    char* ws = (char*)d_ws;
    const size_t WSZ = (size_t)512 * 512 * 2;       // one bf16 weight matrix
    const size_t TSZ = (size_t)16 * 2048 * 64 * 2;  // one head-split bf16 tensor (4 MB)
    short* wT   = (short*)ws;                        // 6 * WSZ = 3 MB
    short* Xb   = (short*)(ws + 6 * WSZ);            // aliased with OUTx
    short* Cb   = (short*)(ws + 6 * WSZ + 1 * TSZ);  // aliased with OUTc
    short* QK   = (short*)(ws + 6 * WSZ + 2 * TSZ);
    short* CQK  = (short*)(ws + 6 * WSZ + 3 * TSZ);
    short* VT   = (short*)(ws + 6 * WSZ + 4 * TSZ);
    short* CVT  = (short*)(ws + 6 * WSZ + 5 * TSZ);  // total ~27.3 MB
    short* OUTx = Xb;
    short* OUTc = Cb;

    prep_kernel<<<dim3(2048, 1, 3), 256, 0, stream>>>(
        x, ctx, w_qk, w_cqk, w_v, w_cv, w_out, w_cout, Xb, Cb, wT);
    proj_kernel<<<dim3(64, 8, 4), 256, 0, stream>>>(Xb, Cb, wT, QK, CQK, VT, CVT);
    attn_kernel<<<dim3(16, 16, 2), 256, 0, stream>>>(QK, CQK, VT, CVT, OUTx, OUTc);
    final_kernel<<<dim3(64, 8, 2), 256, 0, stream>>>(OUTx, OUTc, wT, b_out, b_cout, dout);
}

// Round 6
// 168.049 us; speedup vs baseline: 2.6237x; 1.0423x over previous
//
#include <hip/hip_runtime.h>

#define DEVI __device__ __forceinline__

typedef __attribute__((ext_vector_type(8))) short short8;
typedef __attribute__((ext_vector_type(4))) float f32x4;

struct alignas(8) us4 { unsigned short a, b, c, d; };

DEVI unsigned short f2bf(float f) {
    unsigned int u = __float_as_uint(f);
    u += 0x7fffU + ((u >> 16) & 1U);   // round-to-nearest-even
    return (unsigned short)(u >> 16);
}

DEVI f32x4 mfma16(short8 a, short8 b, f32x4 c) {
    return __builtin_amdgcn_mfma_f32_16x16x32_bf16(a, b, c, 0, 0, 0);
}

// pack two fp32 -> one u32 of two bf16 (round-half-up) in 3 VALU ops:
// lo/hi + 0x8000, then v_perm_b32 grabs the two high halves.
DEVI unsigned pk2(float lo, float hi) {
    unsigned r0 = __float_as_uint(lo) + 0x8000u;
    unsigned r1 = __float_as_uint(hi) + 0x8000u;
    return __builtin_amdgcn_perm(r1, r0, 0x07060302u);
}

DEVI short8 mk8(unsigned a, unsigned b, unsigned c, unsigned d) {
    union { unsigned u[4]; short8 s; } x;
    x.u[0] = a; x.u[1] = b; x.u[2] = c; x.u[3] = d;
    return x.s;
}

// global_load_lds: 16B/lane, LDS dest = wave-uniform base + lane*16 (linear).
#define GLDS(gp, sp) __builtin_amdgcn_global_load_lds( \
    (const __attribute__((address_space(1))) void*)(gp), \
    (__attribute__((address_space(3))) void*)(sp), 16, 0, 0)

#define VMCNT(n) asm volatile("s_waitcnt vmcnt(" #n ")" ::: "memory")

// sqrt(log2(e)/8): pre-scale for QK/CQK so attn does exp2(sim) directly.
#define SQC 0.42466089f

// ---------------------------------------------------------------------------
// prep: z=0/1: x/ctx fp32->bf16; z=2: 6 weight transposes (bf16).
// ---------------------------------------------------------------------------
__global__ __launch_bounds__(256) void prep_kernel(
    const float* __restrict__ x, const float* __restrict__ ctx,
    const float* w0, const float* w1, const float* w2, const float* w3,
    const float* w4, const float* w5,
    short* __restrict__ Xb, short* __restrict__ Cb, short* __restrict__ wT)
{
    int z = blockIdx.z;
    if (z < 2) {
        const float* s = z ? ctx : x;
        short* d = z ? Cb : Xb;
        size_t t = (size_t)blockIdx.x * 256 + threadIdx.x;
        float4 v = *(const float4*)(s + t * 4);
        us4 o = { f2bf(v.x), f2bf(v.y), f2bf(v.z), f2bf(v.w) };
        *(us4*)(d + t * 4) = o;
        return;
    }
    if (blockIdx.x >= 384) return;
    const float* srcs[6] = {w0, w1, w2, w3, w4, w5};
    int wz = blockIdx.x >> 6, rem = blockIdx.x & 63;
    const float* src = srcs[wz];
    short* dst = wT + (size_t)wz * 262144;
    int k0 = (rem >> 3) * 64, n0 = (rem & 7) * 64;
    __shared__ float tile[64][65];
    int t = threadIdx.x;
    int r = t >> 2, c0 = (t & 3) * 16;
#pragma unroll
    for (int ii = 0; ii < 4; ++ii) {
        float4 v = *(const float4*)(src + (size_t)(k0 + r) * 512 + n0 + c0 + ii * 4);
        tile[r][c0 + ii * 4 + 0] = v.x;
        tile[r][c0 + ii * 4 + 1] = v.y;
        tile[r][c0 + ii * 4 + 2] = v.z;
        tile[r][c0 + ii * 4 + 3] = v.w;
    }
    __syncthreads();
#pragma unroll
    for (int ii = 0; ii < 4; ++ii) {
        us4 o;
        o.a = f2bf(tile[c0 + ii * 4 + 0][r]);
        o.b = f2bf(tile[c0 + ii * 4 + 1][r]);
        o.c = f2bf(tile[c0 + ii * 4 + 2][r]);
        o.d = f2bf(tile[c0 + ii * 4 + 3][r]);
        *(us4*)(dst + (size_t)(n0 + r) * 512 + k0 + c0 + ii * 4) = o;
    }
}

// ---------------------------------------------------------------------------
// Input projections. A rows held in registers (16 short8), W double-buffered
// in LDS via global_load_lds + counted vmcnt. p<2 outputs pre-scaled by SQC.
// ---------------------------------------------------------------------------
__global__ __launch_bounds__(256, 4) void proj_kernel(
    const short* __restrict__ Xb, const short* __restrict__ Cb,
    const short* __restrict__ wT,
    short* __restrict__ QK, short* __restrict__ CQK,
    short* __restrict__ VT, short* __restrict__ CVT)
{
    __shared__ __align__(16) char smem[17664];
    short (*wst)[4096] = (short (*)[4096])smem;   // [2][64 rows][8 slots]
    float (*ctile)[69] = (float (*)[69])smem;     // overlaid epilogue buffer

    int p = blockIdx.z;
    const short* src = (p & 1) ? Cb : Xb;
    const short* wm = wT + (size_t)p * 262144;
    int wid = threadIdx.x >> 6, lane = threadIdx.x & 63, il = lane & 15, q = lane >> 4;
    int mb = blockIdx.x * 64, nb = blockIdx.y * 64;
    int srow = lane >> 3, scol8 = ((lane & 7) ^ srow) << 3;
    int key = il & 7;
    const short* wL0 = wm + (size_t)(nb + wid * 16 + srow) * 512 + scol8;
    const short* wL1 = wL0 + 8 * 512;
#define PSTAGE(buf, ck) do { \
    GLDS(wL0 + (ck) * 64, &wst[buf][wid * 1024]); \
    GLDS(wL1 + (ck) * 64, &wst[buf][wid * 1024 + 512]); } while (0)

    PSTAGE(0, 0);
    const short* arow = src + (size_t)(mb + wid * 16 + il) * 512;
    short8 a[16];
#pragma unroll
    for (int j = 0; j < 16; ++j) a[j] = *(const short8*)(arow + j * 32 + (q << 3));

    f32x4 acc[4] = {};
#pragma unroll
    for (int ck = 0; ck < 8; ++ck) {
        int buf = ck & 1;
        if (ck < 7) { PSTAGE(buf ^ 1, ck + 1); VMCNT(2); } else { VMCNT(0); }
        __builtin_amdgcn_s_barrier();
#pragma unroll
        for (int kk = 0; kk < 2; ++kk) {
#pragma unroll
            for (int nj = 0; nj < 4; ++nj) {
                short8 b = *(const short8*)(&wst[buf][(nj * 16 + il) * 64 + ((((kk << 2) + q) ^ key) << 3)]);
                acc[nj] = mfma16(a[ck * 2 + kk], b, acc[nj]);
            }
        }
        asm volatile("" ::: "memory");
        __builtin_amdgcn_s_barrier();
    }
#undef PSTAGE

#pragma unroll
    for (int nj = 0; nj < 4; ++nj)
#pragma unroll
        for (int r = 0; r < 4; ++r)
            ctile[wid * 16 + q * 4 + r][nj * 16 + il] = acc[nj][r];
    __syncthreads();
    int t = threadIdx.x, row = t >> 2, seg = (t & 3) << 4;
    short tmp[16];
    int h = blockIdx.y;
    if (p < 2) {
        short* dst = p ? CQK : QK;
        int i = mb + row, b2 = i >> 11, iL = i & 2047;
#pragma unroll
        for (int e = 0; e < 16; ++e) tmp[e] = (short)f2bf(ctile[row][seg + e] * SQC);
        short* dp = dst + (((size_t)b2 * 8 + h) * 2048 + iL) * 64 + seg;
        *(short8*)dp = *(const short8*)tmp;
        *(short8*)(dp + 8) = *(const short8*)(tmp + 8);
    } else {
        short* dst = (p == 2) ? VT : CVT;
        int d = row;
        int i0 = mb + seg, b2 = i0 >> 11, iL = i0 & 2047;
#pragma unroll
        for (int e = 0; e < 16; ++e) tmp[e] = (short)f2bf(ctile[seg + e][d]);
        short* dp = dst + (((size_t)b2 * 8 + h) * 64 + d) * 2048 + iL;
        *(short8*)dp = *(const short8*)tmp;
        *(short8*)(dp + 8) = *(const short8*)(tmp + 8);
    }
}

// ---------------------------------------------------------------------------
// Fused attention, both directions. 4 waves x 32 rows = 128 rows/block.
// Swapped sim (mfma(K,Q)) + rho-permuted Bt rows => PV A-frag built fully
// in-lane; pack via +0x8000 + v_perm_b32 (3 VALU per bf16 pair).
// Denominator: fp32 per-lane accumulation of unrounded P, reduced over
// q-lanes and redistributed by shuffle in the epilogue (r5-proven).
// ---------------------------------------------------------------------------
__global__ __launch_bounds__(256, 3) void attn_kernel(
    const short* __restrict__ QK, const short* __restrict__ CQK,
    const short* __restrict__ VT, const short* __restrict__ CVT,
    short* __restrict__ OUTx, short* __restrict__ OUTc)
{
    __shared__ __align__(16) short At[8192];     // 128 rows x 64 (16KB)
    __shared__ __align__(16) short Bt[2][4096];  // 64 pos x 64 (2x8KB), rho-permuted rows
    __shared__ __align__(16) short Wt[2][4096];  // 64 d x 64 j (2x8KB)

    int flat = blockIdx.x + (blockIdx.y << 4) + (blockIdx.z << 8);
    int bh = flat & 15;
    int ib = (flat >> 4) & 15;
    int z = flat >> 8;

    const short* Arows = z ? CQK : QK;
    const short* Bcols = z ? QK : CQK;
    const short* WTm   = z ? VT : CVT;
    short* Om          = z ? OUTc : OUTx;

    int b_ = bh >> 3, h = bh & 7;
    int w = threadIdx.x >> 6, lane = threadIdx.x & 63, il = lane & 15, q = lane >> 4;
    const short* Ab = Arows + (size_t)bh * 131072;
    const short* Bb = Bcols + (size_t)bh * 131072;
    const short* Wb = WTm + (size_t)bh * 131072;

    int srow = lane >> 3;
    int scol8 = ((lane & 7) ^ srow) << 3;
    int key = il & 7;

    // Bt row permutation: position p holds source row j(p) with
    // j5=p5, j4=p3, j3=p2, j2=p4, j1=p1, j0=p0.
    int p0 = w * 16 + srow, p1 = p0 + 8;
    int j0p = (p0 & 0x23) | ((p0 & 0x0C) << 1) | ((p0 & 0x10) >> 2);
    int j1p = (p1 & 0x23) | ((p1 & 0x0C) << 1) | ((p1 & 0x10) >> 2);
    const short* BbL0 = Bb + j0p * 64 + scol8;
    const short* BbL1 = Bb + j1p * 64 + scol8;
    const short* WbL0 = Wb + (size_t)p0 * 2048 + scol8;
    const short* WbL1 = WbL0 + 8 * 2048;

#define STAGE(buf, jt) do { \
    GLDS(BbL0 + (jt) * 4096, &Bt[buf][w * 1024]); \
    GLDS(BbL1 + (jt) * 4096, &Bt[buf][w * 1024 + 512]); \
    GLDS(WbL0 + (jt) * 64, &Wt[buf][w * 1024]); \
    GLDS(WbL1 + (jt) * 64, &Wt[buf][w * 1024 + 512]); } while (0)

    // prologue: own 32 A-rows + tile 0
    {
        const short* AbL = Ab + (size_t)(ib * 128 + w * 32 + srow) * 64 + scol8;
        GLDS(AbL, &At[w * 2048]);
        GLDS(AbL + 512, &At[w * 2048 + 512]);
        GLDS(AbL + 1024, &At[w * 2048 + 1024]);
        GLDS(AbL + 1536, &At[w * 2048 + 1536]);
    }
    STAGE(0, 0);
    VMCNT(4);  // own A rows complete

    short8 aq[2][2];
#pragma unroll
    for (int rg = 0; rg < 2; ++rg) {
        const short* base = &At[(w * 32 + rg * 16 + il) * 64];
        aq[rg][0] = *(const short8*)(base + ((q ^ key) << 3));
        aq[rg][1] = *(const short8*)(base + (((q + 4) ^ key) << 3));
    }

    f32x4 acc[2][4] = {};
    float s_acc[2] = {0.f, 0.f};

    for (int jt = 0; jt < 32; ++jt) {
        int cur = jt & 1;
        if (jt < 31) { STAGE(cur ^ 1, jt + 1); VMCNT(4); } else { VMCNT(0); }
        __builtin_amdgcn_s_barrier();

        short8 b0[4], b1[4];
#pragma unroll
        for (int nj = 0; nj < 4; ++nj) {
            const short* bb = &Bt[cur][(nj * 16 + il) * 64];
            b0[nj] = *(const short8*)(bb + ((q ^ key) << 3));
            b1[nj] = *(const short8*)(bb + (((q + 4) ^ key) << 3));
        }

        unsigned pw[2][8];
#pragma unroll
        for (int rg = 0; rg < 2; ++rg) {
#pragma unroll
            for (int nj = 0; nj < 4; ++nj) {
                f32x4 zz = {};
                zz = mfma16(b0[nj], aq[rg][0], zz);
                zz = mfma16(b1[nj], aq[rg][1], zz);
                float e0 = __builtin_amdgcn_exp2f(zz[0]);
                float e1 = __builtin_amdgcn_exp2f(zz[1]);
                float e2 = __builtin_amdgcn_exp2f(zz[2]);
                float e3 = __builtin_amdgcn_exp2f(zz[3]);
                s_acc[rg] += (e0 + e1) + (e2 + e3);
                pw[rg][nj * 2 + 0] = pk2(e0, e1);
                pw[rg][nj * 2 + 1] = pk2(e2, e3);
            }
        }
        short8 pa0[2] = { mk8(pw[0][0], pw[0][1], pw[0][2], pw[0][3]),
                          mk8(pw[1][0], pw[1][1], pw[1][2], pw[1][3]) };
        short8 pa1[2] = { mk8(pw[0][4], pw[0][5], pw[0][6], pw[0][7]),
                          mk8(pw[1][4], pw[1][5], pw[1][6], pw[1][7]) };

#pragma unroll
        for (int nd = 0; nd < 4; ++nd) {
            const short* vv = &Wt[cur][(nd * 16 + il) * 64];
            short8 v0 = *(const short8*)(vv + ((q ^ key) << 3));
            short8 v1 = *(const short8*)(vv + (((q + 4) ^ key) << 3));
#pragma unroll
            for (int rg = 0; rg < 2; ++rg) {
                acc[rg][nd] = mfma16(pa0[rg], v0, acc[rg][nd]);
                acc[rg][nd] = mfma16(pa1[rg], v1, acc[rg][nd]);
            }
        }
        asm volatile("" ::: "memory");
        __builtin_amdgcn_s_barrier();
    }
#undef STAGE

    // Row sums: reduce over q-lanes, redistribute to output-row layout.
    f32x4 inv[2];
#pragma unroll
    for (int rg = 0; rg < 2; ++rg) {
        float s = s_acc[rg];
        s += __shfl_xor(s, 16);
        s += __shfl_xor(s, 32);
#pragma unroll
        for (int r = 0; r < 4; ++r)
            inv[rg][r] = 1.0f / __shfl(s, q * 4 + r);
    }

#pragma unroll
    for (int rg = 0; rg < 2; ++rg) {
#pragma unroll
        for (int nd = 0; nd < 4; ++nd) {
#pragma unroll
            for (int r = 0; r < 4; ++r) {
                int i = ib * 128 + w * 32 + rg * 16 + q * 4 + r;
                Om[((size_t)b_ * 2048 + i) * 512 + h * 64 + nd * 16 + il] =
                    (short)f2bf(acc[rg][nd][r] * inv[rg][r]);
            }
        }
    }
}

// ---------------------------------------------------------------------------
// Output projections (+bias), fp32 out. A in registers, W double-buffered.
// ---------------------------------------------------------------------------
__global__ __launch_bounds__(256, 4) void final_kernel(
    const short* __restrict__ OUTx, const short* __restrict__ OUTc,
    const short* __restrict__ wT,
    const float* __restrict__ b_out, const float* __restrict__ b_cout,
    float* __restrict__ dout)
{
    __shared__ __align__(16) short wst[2][4096];
    int z = blockIdx.z;
    const short* Am = z ? OUTc : OUTx;
    const short* wm = wT + (size_t)(4 + z) * 262144;
    const float* bias = z ? b_cout : b_out;
    float* D = dout + (size_t)z * 2097152;
    int wid = threadIdx.x >> 6, lane = threadIdx.x & 63, il = lane & 15, q = lane >> 4;
    int mb = blockIdx.x * 64, nb = blockIdx.y * 64;
    int srow = lane >> 3, scol8 = ((lane & 7) ^ srow) << 3;
    int key = il & 7;
    const short* wL0 = wm + (size_t)(nb + wid * 16 + srow) * 512 + scol8;
    const short* wL1 = wL0 + 8 * 512;
#define FSTAGE(buf, ck) do { \
    GLDS(wL0 + (ck) * 64, &wst[buf][wid * 1024]); \
    GLDS(wL1 + (ck) * 64, &wst[buf][wid * 1024 + 512]); } while (0)

    FSTAGE(0, 0);
    const short* arow = Am + (size_t)(mb + wid * 16 + il) * 512;
    short8 a[16];
#pragma unroll
    for (int j = 0; j < 16; ++j) a[j] = *(const short8*)(arow + j * 32 + (q << 3));

    f32x4 acc[4] = {};
#pragma unroll
    for (int ck = 0; ck < 8; ++ck) {
        int buf = ck & 1;
        if (ck < 7) { FSTAGE(buf ^ 1, ck + 1); VMCNT(2); } else { VMCNT(0); }
        __builtin_amdgcn_s_barrier();
#pragma unroll
        for (int kk = 0; kk < 2; ++kk) {
#pragma unroll
            for (int nj = 0; nj < 4; ++nj) {
                short8 b = *(const short8*)(&wst[buf][(nj * 16 + il) * 64 + ((((kk << 2) + q) ^ key) << 3)]);
                acc[nj] = mfma16(a[ck * 2 + kk], b, acc[nj]);
            }
        }
        asm volatile("" ::: "memory");
        __builtin_amdgcn_s_barrier();
    }
#undef FSTAGE

#pragma unroll
    for (int nj = 0; nj < 4; ++nj) {
        int c = nb + nj * 16 + il;
        float bi = bias[c];
#pragma unroll
        for (int r = 0; r < 4; ++r) {
            int m = mb + wid * 16 + q * 4 + r;
            D[(size_t)m * 512 + c] = acc[nj][r] + bi;
        }
    }
}

// ---------------------------------------------------------------------------
extern "C" void kernel_launch(void* const* d_in, const int* in_sizes, int n_in,
                              void* d_out, int out_size, void* d_ws, size_t ws_size,
                              hipStream_t stream)
{
    (void)in_sizes; (void)n_in; (void)out_size; (void)ws_size;
    const float* x      = (const float*)d_in[0];
    const float* ctx    = (const float*)d_in[1];
    const float* w_qk   = (const float*)d_in[2];
    const float* w_cqk  = (const float*)d_in[3];
    const float* w_v    = (const float*)d_in[4];
    const float* w_cv   = (const float*)d_in[5];
    const float* w_out  = (const float*)d_in[6];
    const float* b_out  = (const float*)d_in[7];
    const float* w_cout = (const float*)d_in[8];
    const float* b_cout = (const float*)d_in[9];
    float* dout = (float*)d_out;

    char* ws = (char*)d_ws;
    const size_t WSZ = (size_t)512 * 512 * 2;       // one bf16 weight matrix
    const size_t TSZ = (size_t)16 * 2048 * 64 * 2;  // one head-split bf16 tensor (4 MB)
    short* wT   = (short*)ws;                        // 6 * WSZ = 3 MB
    short* Xb   = (short*)(ws + 6 * WSZ);            // aliased with OUTx
    short* Cb   = (short*)(ws + 6 * WSZ + 1 * TSZ);  // aliased with OUTc
    short* QK   = (short*)(ws + 6 * WSZ + 2 * TSZ);
    short* CQK  = (short*)(ws + 6 * WSZ + 3 * TSZ);
    short* VT   = (short*)(ws + 6 * WSZ + 4 * TSZ);
    short* CVT  = (short*)(ws + 6 * WSZ + 5 * TSZ);  // total ~27.3 MB
    short* OUTx = Xb;
    short* OUTc = Cb;

    prep_kernel<<<dim3(2048, 1, 3), 256, 0, stream>>>(
        x, ctx, w_qk, w_cqk, w_v, w_cv, w_out, w_cout, Xb, Cb, wT);
    proj_kernel<<<dim3(64, 8, 4), 256, 0, stream>>>(Xb, Cb, wT, QK, CQK, VT, CVT);
    attn_kernel<<<dim3(16, 16, 2), 256, 0, stream>>>(QK, CQK, VT, CVT, OUTx, OUTc);
    final_kernel<<<dim3(64, 8, 2), 256, 0, stream>>>(OUTx, OUTc, wT, b_out, b_cout, dout);
}